// Round 4
// baseline (477.203 us; speedup 1.0000x reference)
//
#include <hip/hip_runtime.h>

#define PW 88          // sT pitch (floats)
#define SP 84          // sIn pitch (floats)
#define NCOL 82        // staged cols per tile, cj in [0,82) -> staged ti = cj+3
#define IS2 0.70710678118654752f

__device__ __forceinline__ int symidx(int t, int n) {
    t = (t < 0) ? (-1 - t) : t;
    return (t >= n) ? (2 * n - 1 - t) : t;
}

// ---------- issue phase: global loads into registers (prefetch) ----------
__device__ __forceinline__ void issue_yl(float (&st)[9], const float* __restrict__ ylp,
                                         int tid, int r0, int c0)
{
    #pragma unroll
    for (int s = 0; s < 8; ++s) {
        int idx = tid + s * 512;
        if (idx < 44 * NCOL) {
            int er = idx / NCOL;
            int cj = idx - er * NCOL;
            int rr = symidx(r0 - 6 + er, 256);
            int cc = symidx(c0 + cj - 9, 256);
            st[s] = ylp[rr * 256 + cc];
        }
    }
}

template<int NR, int RO, int NS>
__device__ __forceinline__ void issue_c2q(float (&sA)[9], float (&sB)[9],
    const float* __restrict__ yhr, const float* __restrict__ yhi,
    int bA, int bB, int tid, int r0, int c0)
{
    #pragma unroll
    for (int s = 0; s < NS; ++s) {
        int idx = tid + s * 512;
        if (idx < NR * NCOL) {
            int er = idx / NCOL;
            int cj = idx - er * NCOL;
            int rr = symidx(r0 - RO + er, 256);
            int cc = symidx(c0 + cj - 9, 256);
            int rp = rr & 1, cp = cc & 1;
            const float* base = (((rp ^ cp) != 0) ? yhi : yhr) + ((rr >> 1) * 128 + (cc >> 1));
            sA[s] = base[bA * 16384];
            sB[s] = base[bB * 16384];
        }
    }
}

// ---------- write phase: regs -> sIn (c2q combine at write time) ----------
__device__ __forceinline__ void write_yl(float* sIn, const float (&st)[9], int tid)
{
    #pragma unroll
    for (int s = 0; s < 8; ++s) {
        int idx = tid + s * 512;
        if (idx < 44 * NCOL) {
            int er = idx / NCOL;
            int cj = idx - er * NCOL;
            sIn[er * SP + cj] = st[s];
        }
    }
}

template<int NR, int RO, int NS>
__device__ __forceinline__ void write_c2q(float* sIn, const float (&sA)[9], const float (&sB)[9],
                                          int tid, int r0, int c0)
{
    #pragma unroll
    for (int s = 0; s < NS; ++s) {
        int idx = tid + s * 512;
        if (idx < NR * NCOL) {
            int er = idx / NCOL;
            int cj = idx - er * NCOL;
            int rp = symidx(r0 - RO + er, 256) & 1;
            int cp = symidx(c0 + cj - 9, 256) & 1;
            float A = sA[s], B = sB[s];
            float vA = (rp & cp) ? -A : A;
            float vB = (rp & (cp ^ 1)) ? -B : B;
            sIn[er * SP + cj] = (vA + vB) * IS2;
        }
    }
}

// ---------- compute phase: column filter sIn -> sT[comp], 4-row strips ----------
template<int L>
__device__ __forceinline__ void col_compute(float* sTk, const float* sIn,
                                            const float* __restrict__ taps, int tid)
{
    #pragma unroll
    for (int pass = 0; pass < 2; ++pass) {
        int idx = tid + pass * 512;
        if (idx < 8 * NCOL) {
            int g  = idx / NCOL;
            int cj = idx - g * NCOL;
            int R  = 4 * g;
            const float* q = sIn + R * SP + cj;
            float a0 = 0.f, a1 = 0.f, a2 = 0.f, a3 = 0.f;
            #pragma unroll
            for (int t = 0; t < L + 3; ++t) {
                float v = q[t * SP];
                if (t < L)              a0 = fmaf(taps[L - 1 - t], v, a0);
                if (t >= 1 && t < L+1)  a1 = fmaf(taps[L     - t], v, a1);
                if (t >= 2 && t < L+2)  a2 = fmaf(taps[L + 1 - t], v, a2);
                if (t >= 3)             a3 = fmaf(taps[L + 2 - t], v, a3);
            }
            sTk[(R + 0) * PW + cj + 3] = a0;
            sTk[(R + 1) * PW + cj + 3] = a1;
            sTk[(R + 2) * PW + cj + 3] = a2;
            sTk[(R + 3) * PW + cj + 3] = a3;
        }
    }
}

extern "C" __global__ __launch_bounds__(512) void dtcwt_inv(
    const float* __restrict__ Yl, const float* __restrict__ Yhr,
    const float* __restrict__ Yhi,
    const float* __restrict__ g0, const float* __restrict__ g1,
    const float* __restrict__ g2, float* __restrict__ out)
{
    __shared__ __align__(16) float sT[4][32][PW];
    __shared__ __align__(16) float sIn[50 * SP];

    const int tid = threadIdx.x;
    const int plane = blockIdx.z;
    const int r0 = blockIdx.y * 32;
    const int c0 = blockIdx.x * 64;

    const float* ylp = Yl  + (size_t)plane * 65536;
    const float* yhr = Yhr + (size_t)plane * 6 * 16384;
    const float* yhi = Yhi + (size_t)plane * 6 * 16384;

    float stA[9], stB[9];

    // comp0 = Yl (col g0 -> sT[0])
    issue_yl(stA, ylp, tid, r0, c0);
    write_yl(sIn, stA, tid);
    __syncthreads();

    // prefetch lh (bands 0,5) while computing Yl column filter
    issue_c2q<50, 9, 9>(stA, stB, yhr, yhi, 0, 5, tid, r0, c0);
    col_compute<13>(&sT[0][0][0], sIn, g0, tid);
    __syncthreads();
    write_c2q<50, 9, 9>(sIn, stA, stB, tid, r0, c0);
    __syncthreads();

    // prefetch hl (bands 2,3) while computing lh column filter (g1, 19 taps)
    issue_c2q<44, 6, 8>(stA, stB, yhr, yhi, 2, 3, tid, r0, c0);
    col_compute<19>(&sT[1][0][0], sIn, g1, tid);
    __syncthreads();
    write_c2q<44, 6, 8>(sIn, stA, stB, tid, r0, c0);
    __syncthreads();

    // prefetch hh (bands 1,4) while computing hl column filter (g0)
    issue_c2q<44, 6, 8>(stA, stB, yhr, yhi, 1, 4, tid, r0, c0);
    col_compute<13>(&sT[2][0][0], sIn, g0, tid);
    __syncthreads();
    write_c2q<44, 6, 8>(sIn, stA, stB, tid, r0, c0);
    __syncthreads();

    // hh column filter (g2)
    col_compute<13>(&sT[3][0][0], sIn, g2, tid);
    __syncthreads();

    // ---------------- stage 2: row filters from LDS -> 4 outputs/thread ----------------
    const int cg = tid & 15;
    const int r  = tid >> 4;
    const int cb = 4 * cg;

    float w1[20];
    #pragma unroll
    for (int k = 0; k < 5; ++k) {
        float4 a = *(const float4*)&sT[0][r][cb + 4 + 4 * k];
        float4 b = *(const float4*)&sT[1][r][cb + 4 + 4 * k];
        w1[4*k+0] = a.x + b.x; w1[4*k+1] = a.y + b.y;
        w1[4*k+2] = a.z + b.z; w1[4*k+3] = a.w + b.w;
    }
    float w2[28];
    #pragma unroll
    for (int k = 0; k < 7; ++k) {
        float4 a = *(const float4*)&sT[2][r][cb + 4 * k];
        w2[4*k+0] = a.x; w2[4*k+1] = a.y; w2[4*k+2] = a.z; w2[4*k+3] = a.w;
    }
    float w3[20];
    #pragma unroll
    for (int k = 0; k < 5; ++k) {
        float4 a = *(const float4*)&sT[3][r][cb + 4 + 4 * k];
        w3[4*k+0] = a.x; w3[4*k+1] = a.y; w3[4*k+2] = a.z; w3[4*k+3] = a.w;
    }

    float4 res;
    float* rp = (float*)&res;
    #pragma unroll
    for (int q = 0; q < 4; ++q) {
        float s = 0.0f;
        #pragma unroll
        for (int j = 0; j < 13; ++j) s = fmaf(g0[j], w1[q + 14 - j], s);
        #pragma unroll
        for (int j = 0; j < 19; ++j) s = fmaf(g1[j], w2[q + 21 - j], s);
        #pragma unroll
        for (int j = 0; j < 13; ++j) s = fmaf(g2[j], w3[q + 14 - j], s);
        rp[q] = s;
    }
    *(float4*)&out[(size_t)plane * 65536 + (size_t)(r0 + r) * 256 + (c0 + cb)] = res;
}

extern "C" void kernel_launch(void* const* d_in, const int* in_sizes, int n_in,
                              void* d_out, int out_size, void* d_ws, size_t ws_size,
                              hipStream_t stream) {
    const float* Yl  = (const float*)d_in[0];
    const float* Yhr = (const float*)d_in[1];
    const float* Yhi = (const float*)d_in[2];
    const float* g0  = (const float*)d_in[3];
    const float* g1  = (const float*)d_in[4];
    const float* g2  = (const float*)d_in[5];
    float* out = (float*)d_out;

    dim3 grid(256 / 64, 256 / 32, 8 * 64);   // (4, 8, 512)
    dim3 block(512, 1, 1);
    dtcwt_inv<<<grid, block, 0, stream>>>(Yl, Yhr, Yhi, g0, g1, g2, out);
}

// Round 5
// 397.635 us; speedup vs baseline: 1.2001x; 1.2001x over previous
//
#include <hip/hip_runtime.h>

#define TH 32
#define TW 64
#define PW 88   // LDS row pitch in floats
#define IS2 0.70710678118654752f

__device__ __forceinline__ int symidx(int t, int n) {
    t = (t < 0) ? (-1 - t) : t;
    return (t >= n) ? (2 * n - 1 - t) : t;
}

// ================= border-path helpers (r1, proven) =================
__device__ __forceinline__ void col13_yl(
    float (&acc)[TH], const float* __restrict__ ylp,
    const float* __restrict__ taps, int r0, int cc)
{
    #pragma unroll
    for (int pi = 0; pi < TH + 12; ++pi) {
        int rr = symidx(r0 - 6 + pi, 256);
        float v = ylp[rr * 256 + cc];
        #pragma unroll
        for (int j = 0; j < 13; ++j) {
            int ro = pi + j - 12;
            if (ro >= 0 && ro < TH) acc[ro] = fmaf(taps[j], v, acc[ro]);
        }
    }
}

__device__ __forceinline__ void col13_c2q(
    float (&acc)[TH], const float* __restrict__ yhr, const float* __restrict__ yhi,
    int bA, int bB, const float* __restrict__ taps, int r0, int cc)
{
    const int cp = cc & 1;
    const int j2 = cc >> 1;
    #pragma unroll
    for (int pi = 0; pi < TH + 12; ++pi) {
        int rr = symidx(r0 - 6 + pi, 256);
        int rp = rr & 1;
        int i2 = rr >> 1;
        const float* base = (((rp ^ cp) != 0) ? yhi : yhr) + (i2 * 128 + j2);
        float A  = base[bA * 16384];
        float Bv = base[bB * 16384];
        float vA = (rp & cp)       ? -A  : A;
        float vB = (rp & (cp ^ 1)) ? -Bv : Bv;
        float v = (vA + vB) * IS2;
        #pragma unroll
        for (int j = 0; j < 13; ++j) {
            int ro = pi + j - 12;
            if (ro >= 0 && ro < TH) acc[ro] = fmaf(taps[j], v, acc[ro]);
        }
    }
}

__device__ __forceinline__ void col19_c2q(
    float (&acc)[TH], const float* __restrict__ yhr, const float* __restrict__ yhi,
    const float* __restrict__ taps, int r0, int cc)
{
    const int bA = 0, bB = 5;
    const int cp = cc & 1;
    const int j2 = cc >> 1;
    #pragma unroll
    for (int pi = 0; pi < TH + 18; ++pi) {
        int rr = symidx(r0 - 9 + pi, 256);
        int rp = rr & 1;
        int i2 = rr >> 1;
        const float* base = (((rp ^ cp) != 0) ? yhi : yhr) + (i2 * 128 + j2);
        float A  = base[bA * 16384];
        float Bv = base[bB * 16384];
        float vA = (rp & cp)       ? -A  : A;
        float vB = (rp & (cp ^ 1)) ? -Bv : Bv;
        float v = (vA + vB) * IS2;
        #pragma unroll
        for (int j = 0; j < 19; ++j) {
            int ro = pi + j - 18;
            if (ro >= 0 && ro < TH) acc[ro] = fmaf(taps[j], v, acc[ro]);
        }
    }
}

// ===== interior fast helper: single column, row-pair c2q, distance-PF prefetch =====
template<int L, int NP, int EPI0, int PF>
__device__ __forceinline__ void c2q_col_fast1(
    float (&acc)[TH],
    const float* __restrict__ pEA, const float* __restrict__ pEB,
    const float* __restrict__ pOA, const float* __restrict__ pOB,
    int vof, float sgn, const float* __restrict__ taps)
{
    float vAe[PF], vBe[PF], vAo[PF], vBo[PF];
    #pragma unroll
    for (int u = 0; u < PF; ++u) {
        vAe[u] = pEA[vof + u * 128];
        vBe[u] = pEB[vof + u * 128];
        vAo[u] = pOA[vof + u * 128];
        vBo[u] = pOB[vof + u * 128];
    }
    #pragma unroll
    for (int u = 0; u < NP; ++u) {
        const int slot = u % PF;              // compile-time after unroll
        float ve = (vAe[slot] + vBe[slot]) * IS2;
        float vo = (vAo[slot] - vBo[slot]) * sgn;
        if (u + PF < NP) {                    // prefetch pair u+PF into freed slot
            vAe[slot] = pEA[vof + (u + PF) * 128];
            vBe[slot] = pEB[vof + (u + PF) * 128];
            vAo[slot] = pOA[vof + (u + PF) * 128];
            vBo[slot] = pOB[vof + (u + PF) * 128];
        }
        #pragma unroll
        for (int j = 0; j < L; ++j) {
            int ro = EPI0 + 2 * u + j - (L - 1);
            if (ro >= 0 && ro < TH) acc[ro] = fmaf(taps[j], ve, acc[ro]);
        }
        #pragma unroll
        for (int j = 0; j < L; ++j) {
            int ro = EPI0 + 2 * u + 1 + j - (L - 1);
            if (ro >= 0 && ro < TH) acc[ro] = fmaf(taps[j], vo, acc[ro]);
        }
    }
}

extern "C" __global__ __launch_bounds__(512, 6) void dtcwt_inv(
    const float* __restrict__ Yl, const float* __restrict__ Yhr,
    const float* __restrict__ Yhi,
    const float* __restrict__ g0, const float* __restrict__ g1,
    const float* __restrict__ g2, float* __restrict__ out)
{
    __shared__ __align__(16) float sT[4][TH][PW];

    const int tid = threadIdx.x;
    // bijective XCD swizzle: 16384 blocks = 8 XCDs x 2048; each XCD gets
    // 64 contiguous planes -> halo re-reads stay in its own L2.
    const int wg  = blockIdx.x;
    const int swz = (wg & 7) * 2048 + (wg >> 3);
    const int plane = swz >> 5;
    const int bt = swz & 31;
    const int bx = bt & 3;
    const int by = bt >> 2;
    const int r0 = by * TH;
    const int c0 = bx * TW;

    const float* ylp = Yl  + (size_t)plane * 65536;
    const float* yhr = Yhr + (size_t)plane * 6 * 16384;
    const float* yhi = Yhi + (size_t)plane * 6 * 16384;

    const bool rowInterior = (by >= 1) && (by <= 6);

    const int role = tid >> 7;
    const int lr   = tid & 127;

    float acc[TH];
    #pragma unroll
    for (int i = 0; i < TH; ++i) acc[i] = 0.0f;
    int ti = -1;

    if (rowInterior) {
        // ---------- fast stage 1: no row symidx, row-pair c2q, prefetched ----------
        if (role == 0) {
            if (lr < 76) {
                ti = lr + 6;
                int cc = symidx(c0 + lr - 6, 256);
                const float* p = ylp + (r0 - 6) * 256 + cc;
                float pv[8];
                #pragma unroll
                for (int s = 0; s < 8; ++s) pv[s] = p[s * 256];
                #pragma unroll
                for (int pi = 0; pi < TH + 12; ++pi) {
                    const int slot = pi % 8;
                    float v = pv[slot];
                    if (pi + 8 < TH + 12) pv[slot] = p[(pi + 8) * 256];
                    #pragma unroll
                    for (int j = 0; j < 13; ++j) {
                        int ro = pi + j - 12;
                        if (ro >= 0 && ro < TH) acc[ro] = fmaf(g0[j], v, acc[ro]);
                    }
                }
            }
        } else if (role == 1) {
            if (lr < 76) {                        // t1b = col_g1(lh), bands 0,5
                ti = lr + 6;
                int cc = symidx(c0 + lr - 6, 256);
                int cp = cc & 1, j2 = cc >> 1;
                const float* pE = cp ? yhi : yhr;
                const float* pO = cp ? yhr : yhi;
                float sgn = cp ? -IS2 : IS2;
                int vof = ((r0 - 10) >> 1) * 128 + j2;
                c2q_col_fast1<19, 26, -1, 5>(acc,
                    pE + 0 * 16384, pE + 5 * 16384,
                    pO + 0 * 16384, pO + 5 * 16384, vof, sgn, g1);
            }
        } else if (role == 2) {
            if (lr < 82) {                        // t2 = col_g0(hl), bands 2,3
                ti = lr + 3;
                int cc = symidx(c0 + lr - 9, 256);
                int cp = cc & 1, j2 = cc >> 1;
                const float* pE = cp ? yhi : yhr;
                const float* pO = cp ? yhr : yhi;
                float sgn = cp ? -IS2 : IS2;
                int vof = ((r0 - 6) >> 1) * 128 + j2;
                c2q_col_fast1<13, 22, 0, 5>(acc,
                    pE + 2 * 16384, pE + 3 * 16384,
                    pO + 2 * 16384, pO + 3 * 16384, vof, sgn, g0);
            }
        } else {
            if (lr < 76) {                        // t3 = col_g2(hh), bands 1,4
                ti = lr + 6;
                int cc = symidx(c0 + lr - 6, 256);
                int cp = cc & 1, j2 = cc >> 1;
                const float* pE = cp ? yhi : yhr;
                const float* pO = cp ? yhr : yhi;
                float sgn = cp ? -IS2 : IS2;
                int vof = ((r0 - 6) >> 1) * 128 + j2;
                c2q_col_fast1<13, 22, 0, 5>(acc,
                    pE + 1 * 16384, pE + 4 * 16384,
                    pO + 1 * 16384, pO + 4 * 16384, vof, sgn, g2);
            }
        }
    } else {
        // ---------- border stage 1 (r1 path, handles row reflection) ----------
        if (role == 0) {
            if (lr < 76) {
                ti = lr + 6;
                int cc = symidx(c0 + ti - 12, 256);
                col13_yl(acc, ylp, g0, r0, cc);
            }
        } else if (role == 1) {
            if (lr < 76) {
                ti = lr + 6;
                int cc = symidx(c0 + ti - 12, 256);
                col19_c2q(acc, yhr, yhi, g1, r0, cc);
            }
        } else if (role == 2) {
            if (lr < 82) {
                ti = lr + 3;
                int cc = symidx(c0 + ti - 12, 256);
                col13_c2q(acc, yhr, yhi, 2, 3, g0, r0, cc);
            }
        } else {
            if (lr < 76) {
                ti = lr + 6;
                int cc = symidx(c0 + ti - 12, 256);
                col13_c2q(acc, yhr, yhi, 1, 4, g2, r0, cc);
            }
        }
    }
    if (ti >= 0) {
        #pragma unroll
        for (int ro = 0; ro < TH; ++ro) sT[role][ro][ti] = acc[ro];
    }
    __syncthreads();

    // ---------------- stage 2: row filters from LDS -> 4 outputs/thread ----------------
    const int cg = tid & 15;
    const int r  = tid >> 4;
    const int cb = 4 * cg;

    float w1[20];
    #pragma unroll
    for (int k = 0; k < 5; ++k) {
        float4 a = *(const float4*)&sT[0][r][cb + 4 + 4 * k];
        float4 b = *(const float4*)&sT[1][r][cb + 4 + 4 * k];
        w1[4*k+0] = a.x + b.x; w1[4*k+1] = a.y + b.y;
        w1[4*k+2] = a.z + b.z; w1[4*k+3] = a.w + b.w;
    }
    float w2[28];
    #pragma unroll
    for (int k = 0; k < 7; ++k) {
        float4 a = *(const float4*)&sT[2][r][cb + 4 * k];
        w2[4*k+0] = a.x; w2[4*k+1] = a.y; w2[4*k+2] = a.z; w2[4*k+3] = a.w;
    }
    float w3[20];
    #pragma unroll
    for (int k = 0; k < 5; ++k) {
        float4 a = *(const float4*)&sT[3][r][cb + 4 + 4 * k];
        w3[4*k+0] = a.x; w3[4*k+1] = a.y; w3[4*k+2] = a.z; w3[4*k+3] = a.w;
    }

    float4 res;
    float* rp = (float*)&res;
    #pragma unroll
    for (int q = 0; q < 4; ++q) {
        float s = 0.0f;
        #pragma unroll
        for (int j = 0; j < 13; ++j) s = fmaf(g0[j], w1[q + 14 - j], s);
        #pragma unroll
        for (int j = 0; j < 19; ++j) s = fmaf(g1[j], w2[q + 21 - j], s);
        #pragma unroll
        for (int j = 0; j < 13; ++j) s = fmaf(g2[j], w3[q + 14 - j], s);
        rp[q] = s;
    }
    *(float4*)&out[(size_t)plane * 65536 + (size_t)(r0 + r) * 256 + (c0 + cb)] = res;
}

extern "C" void kernel_launch(void* const* d_in, const int* in_sizes, int n_in,
                              void* d_out, int out_size, void* d_ws, size_t ws_size,
                              hipStream_t stream) {
    const float* Yl  = (const float*)d_in[0];
    const float* Yhr = (const float*)d_in[1];
    const float* Yhi = (const float*)d_in[2];
    const float* g0  = (const float*)d_in[3];
    const float* g1  = (const float*)d_in[4];
    const float* g2  = (const float*)d_in[5];
    float* out = (float*)d_out;

    dim3 grid(16384, 1, 1);   // 1D, XCD-swizzled in-kernel
    dim3 block(512, 1, 1);
    dtcwt_inv<<<grid, block, 0, stream>>>(Yl, Yhr, Yhi, g0, g1, g2, out);
}